// Round 1
// baseline (28777.133 us; speedup 1.0000x reference)
//
#include <hip/hip_runtime.h>
#include <stdint.h>

// Problem constants
#define kS 256      // sequence length
#define kB 256      // batch
#define kE 300      // embedding dim
#define kH 300      // hidden per direction
#define kG 1200     // 4*H gates
#define kT 9        // tags
#define TILE_B 2    // batch rows per block
#define TCHUNK 4    // timesteps per input-projection chunk

#define EMSZ (kS * kB * kT)   // floats per direction of emission buffer

__device__ __forceinline__ float sigmoidf_(float v) { return 1.0f / (1.0f + expf(-v)); }

// -----------------------------------------------------------------------------
// Fused BiLSTM kernel: one block = (direction, 2-batch-row tile). Runs the whole
// 256-step recurrence locally (h,c in LDS), fuses embedding gather, input
// projection (chunked over 4 steps to amortize w_ih streaming), recurrent GEMM,
// gate nonlinearities, and the per-direction emission projection.
// Writes em_dir[s][b][tag] (fp32) to workspace.
// -----------------------------------------------------------------------------
__global__ __launch_bounds__(256) void ner_bilstm_kernel(
    const int*   __restrict__ x,        // [B][S]
    const float* __restrict__ emb,      // [V][E]
    const float* __restrict__ w_ih_f,   // [1200][300]
    const float* __restrict__ w_hh_f,   // [1200][300]
    const float* __restrict__ b_ih_f,   // [1200]
    const float* __restrict__ b_hh_f,   // [1200]
    const float* __restrict__ w_ih_b,
    const float* __restrict__ w_hh_b,
    const float* __restrict__ b_ih_b,
    const float* __restrict__ b_hh_b,
    const float* __restrict__ w_proj,   // [9][600]
    float*       __restrict__ em_all)   // ws: em_f then em_b, each [S][B][9]
{
    // XCD-grouped mapping: XCDs 0-3 forward, 4-7 backward => each XCD's L2 only
    // holds one direction's weights (2.88 MB < 4 MB), avoiding thrash.
    const int bi   = blockIdx.x;
    const int xcd  = bi & 7;
    const int dir  = (xcd >= 4) ? 1 : 0;
    const int tile = (bi >> 3) * 4 + (xcd & 3);   // 0..127

    const float* wih = dir ? w_ih_b : w_ih_f;
    const float* whh = dir ? w_hh_b : w_hh_f;
    const float* bih = dir ? b_ih_b : b_ih_f;
    const float* bhh = dir ? b_hh_b : b_hh_f;
    float* emout = em_all + (size_t)dir * EMSZ;

    __shared__ float s_h[TILE_B][304];                 // h_{t-1}, 16B-aligned rows
    __shared__ float s_c[TILE_B][300];
    __shared__ float s_Ax[TCHUNK * TILE_B][304];       // gathered embeddings (chunk)
    __shared__ float s_pre[TCHUNK][TILE_B][kG];        // bias + x@w_ih^T for chunk
    __shared__ float s_gbuf[TILE_B][kG];               // gate preacts for current step
    __shared__ float s_emp[TILE_B][kT][14];            // emission partial sums
    // NOTE: kernel launched with 57344 B dynamic LDS (unused) to force 1 block/CU.

    const int tid = threadIdx.x;

    // init h = c = 0
    for (int i = tid; i < TILE_B * 304; i += 256) (&s_h[0][0])[i] = 0.0f;
    for (int i = tid; i < TILE_B * 300; i += 256) (&s_c[0][0])[i] = 0.0f;
    __syncthreads();

    for (int tc = 0; tc < kS / TCHUNK; ++tc) {
        // ---- embedding gather for this time chunk -------------------------------
        {
            const int rr   = tid >> 5;        // 0..7 = (tt, b)
            const int lane = tid & 31;
            const int tt   = rr >> 1;
            const int b2   = rr & 1;
            const int t    = tc * TCHUNK + tt;
            const int s    = dir ? (kS - 1 - t) : t;
            const int bg   = tile * TILE_B + b2;
            const int token = x[bg * kS + s];
            const float* erow = emb + (size_t)token * kE;
            for (int e = lane; e < kE; e += 32) s_Ax[rr][e] = erow[e];
        }
        __syncthreads();

        // ---- input projection: pre[tt][b][g] = bias[g] + x_t . w_ih[g] ----------
        if (tid < 240) {
            const int r0 = tid * 5;           // 5 consecutive gate rows per thread
            float acc[5][8];
#pragma unroll
            for (int j = 0; j < 5; ++j) {
                const float bs = bih[r0 + j] + bhh[r0 + j];
#pragma unroll
                for (int q = 0; q < 8; ++q) acc[j][q] = bs;
            }
            for (int kc = 0; kc < 75; ++kc) {
                float4 a[8];
#pragma unroll
                for (int q = 0; q < 8; ++q)
                    a[q] = *(const float4*)&s_Ax[q][kc * 4];
#pragma unroll
                for (int j = 0; j < 5; ++j) {
                    const float4 w = *(const float4*)&wih[(r0 + j) * kE + kc * 4];
#pragma unroll
                    for (int q = 0; q < 8; ++q)
                        acc[j][q] += w.x * a[q].x + w.y * a[q].y + w.z * a[q].z + w.w * a[q].w;
                }
            }
#pragma unroll
            for (int j = 0; j < 5; ++j)
#pragma unroll
                for (int tt = 0; tt < TCHUNK; ++tt)
#pragma unroll
                    for (int b2 = 0; b2 < TILE_B; ++b2)
                        s_pre[tt][b2][r0 + j] = acc[j][tt * 2 + b2];
        }
        __syncthreads();

        // ---- recurrent steps within the chunk -----------------------------------
        for (int tt = 0; tt < TCHUNK; ++tt) {
            const int t = tc * TCHUNK + tt;
            const int s = dir ? (kS - 1 - t) : t;

            // gates = pre + h_{t-1} @ w_hh^T
            if (tid < 240) {
                const int r0 = tid * 5;
                float acc[5][2];
#pragma unroll
                for (int j = 0; j < 5; ++j) {
                    acc[j][0] = s_pre[tt][0][r0 + j];
                    acc[j][1] = s_pre[tt][1][r0 + j];
                }
                for (int kc = 0; kc < 75; ++kc) {
                    const float4 a0 = *(const float4*)&s_h[0][kc * 4];
                    const float4 a1 = *(const float4*)&s_h[1][kc * 4];
#pragma unroll
                    for (int j = 0; j < 5; ++j) {
                        const float4 w = *(const float4*)&whh[(r0 + j) * kH + kc * 4];
                        acc[j][0] += w.x * a0.x + w.y * a0.y + w.z * a0.z + w.w * a0.w;
                        acc[j][1] += w.x * a1.x + w.y * a1.y + w.z * a1.z + w.w * a1.w;
                    }
                }
#pragma unroll
                for (int j = 0; j < 5; ++j) {
                    s_gbuf[0][r0 + j] = acc[j][0];
                    s_gbuf[1][r0 + j] = acc[j][1];
                }
            }
            __syncthreads();

            // elementwise LSTM cell update (PyTorch gate order i,f,g,o)
#pragma unroll
            for (int rep = 0; rep < 2; ++rep) {
                const int nn = tid + rep * 256;
                if (nn < kH) {
#pragma unroll
                    for (int b2 = 0; b2 < TILE_B; ++b2) {
                        const float gi = s_gbuf[b2][nn];
                        const float gf = s_gbuf[b2][nn + 300];
                        const float gg = s_gbuf[b2][nn + 600];
                        const float go = s_gbuf[b2][nn + 900];
                        const float c  = sigmoidf_(gf) * s_c[b2][nn] + sigmoidf_(gi) * tanhf(gg);
                        const float h  = sigmoidf_(go) * tanhf(c);
                        s_c[b2][nn] = c;
                        s_h[b2][nn] = h;
                    }
                }
            }
            __syncthreads();

            // emission partials: em_dir[s][b][tag] = sum_n h[b][n] * w_proj[tag][dir*300 + n]
            if (tid < 252) {
                const int b2  = tid / 126;
                const int rem = tid % 126;
                const int tag = rem / 14;
                const int ch  = rem % 14;
                const int n0  = ch * 22;
                const int n1  = (n0 + 22 < 300) ? n0 + 22 : 300;
                const float* wrow = w_proj + tag * (2 * kH) + dir * kH;
                float sum = 0.0f;
                for (int n = n0; n < n1; ++n) sum += s_h[b2][n] * wrow[n];
                s_emp[b2][tag][ch] = sum;
            }
            __syncthreads();

            if (tid < TILE_B * kT) {
                const int b2  = tid / kT;
                const int tag = tid % kT;
                float sum = 0.0f;
#pragma unroll
                for (int ch = 0; ch < 14; ++ch) sum += s_emp[b2][tag][ch];
                const int bg = tile * TILE_B + b2;
                emout[((size_t)s * kB + bg) * kT + tag] = sum;
            }
            // next h-phase only reads s_h/s_pre (stable); s_emp rewritten only after
            // two more barriers next iteration — no extra sync needed here.
        }
    }
}

// -----------------------------------------------------------------------------
// CRF Viterbi decode. 9 lanes per batch row (7 groups/wave, 28 rows/block).
// Cross-lane max via __shfl (no barriers in DP loop). Backpointers in LDS.
// First-max tie-breaking matches np.argmax.
// -----------------------------------------------------------------------------
__global__ __launch_bounds__(256) void ner_viterbi_kernel(
    const float* __restrict__ em_all,      // ws: em_f, em_b
    const float* __restrict__ b_proj,      // [9]
    const float* __restrict__ start_t,     // [9]
    const float* __restrict__ end_t,       // [9]
    const float* __restrict__ trans,       // [9][9]
    int*         __restrict__ out)         // [B][S] int32
{
    const float* em_f = em_all;
    const float* em_b = em_all + EMSZ;

    __shared__ uint8_t bp[kS - 1][28][kT];   // 64,260 B

    const int tid  = threadIdx.x;
    const int wave = tid >> 6;
    const int lane = tid & 63;
    const int g    = lane / kT;             // 0..7 (7 is idle)
    const int nx   = lane % kT;
    const bool active = (g < 7);
    const int gg   = wave * 7 + g;          // 0..27 (when active)
    const int b    = blockIdx.x * 28 + (active ? gg : 0);
    const bool valid = active && (b < kB);
    const int beff = (b < kB) ? b : (kB - 1);
    const int base = g * kT;                // first lane of my group

    float tcol[kT];
#pragma unroll
    for (int p = 0; p < kT; ++p) tcol[p] = trans[p * kT + nx];
    const float bpj = b_proj[nx];

    float score = start_t[nx]
                + em_f[(size_t)beff * kT + nx]
                + em_b[(size_t)beff * kT + nx]
                + bpj;

    for (int t = 1; t < kS; ++t) {
        const size_t ei = ((size_t)t * kB + beff) * kT + nx;
        const float em = em_f[ei] + em_b[ei] + bpj;
        float best = -3.402823466e38f;
        int bidx = 0;
#pragma unroll
        for (int p = 0; p < kT; ++p) {
            const float sp = __shfl(score, base + p, 64);
            const float cand = sp + tcol[p];
            if (cand > best) { best = cand; bidx = p; }
        }
        if (valid) bp[t - 1][gg][nx] = (uint8_t)bidx;
        score = best + em;
    }

    score += end_t[nx];
    float best = -3.402823466e38f;
    int last = 0;
#pragma unroll
    for (int p = 0; p < kT; ++p) {
        const float sp = __shfl(score, base + p, 64);
        if (sp > best) { best = sp; last = p; }
    }

    __syncthreads();   // bp writes visible across lanes

    if (valid && nx == 0) {
        int cur = last;
        out[beff * kS + (kS - 1)] = cur;
        for (int t = kS - 2; t >= 0; --t) {
            cur = bp[t][gg][cur];
            out[beff * kS + t] = cur;
        }
    }
}

// -----------------------------------------------------------------------------
extern "C" void kernel_launch(void* const* d_in, const int* in_sizes, int n_in,
                              void* d_out, int out_size, void* d_ws, size_t ws_size,
                              hipStream_t stream) {
    const int*   x         = (const int*)  d_in[0];
    const float* emb       = (const float*)d_in[1];
    const float* w_ih_f    = (const float*)d_in[2];
    const float* w_hh_f    = (const float*)d_in[3];
    const float* b_ih_f    = (const float*)d_in[4];
    const float* b_hh_f    = (const float*)d_in[5];
    const float* w_ih_b    = (const float*)d_in[6];
    const float* w_hh_b    = (const float*)d_in[7];
    const float* b_ih_b    = (const float*)d_in[8];
    const float* b_hh_b    = (const float*)d_in[9];
    const float* w_proj    = (const float*)d_in[10];
    const float* b_proj    = (const float*)d_in[11];
    const float* start_t   = (const float*)d_in[12];
    const float* end_t     = (const float*)d_in[13];
    const float* trans     = (const float*)d_in[14];

    float* em_all = (float*)d_ws;          // 2 * EMSZ floats = 4.7 MB
    int*   out    = (int*)d_out;

    // 256 blocks (2 dirs x 128 tiles), 57 KB dummy dynamic LDS forces 1 block/CU.
    ner_bilstm_kernel<<<256, 256, 57344, stream>>>(
        x, emb, w_ih_f, w_hh_f, b_ih_f, b_hh_f,
        w_ih_b, w_hh_b, b_ih_b, b_hh_b, w_proj, em_all);

    ner_viterbi_kernel<<<10, 256, 0, stream>>>(
        em_all, b_proj, start_t, end_t, trans, out);
}

// Round 2
// 6903.337 us; speedup vs baseline: 4.1686x; 4.1686x over previous
//
#include <hip/hip_runtime.h>
#include <stdint.h>

// Problem constants
#define kS 256      // sequence length
#define kB 256      // batch
#define kE 300      // embedding dim
#define kH 300      // hidden per direction
#define kG 1200     // 4*H gate rows
#define kT 9        // tags
#define TILE_B 2    // batch rows per block
#define TCHUNK 8    // timesteps per input-projection chunk
#define RPT 5       // gate rows per thread
#define ACT 240     // active threads in GEMM phases (240*5 = 1200)

#define EMSZ (kS * kB * kT)   // floats per direction of emission buffer
#define W4   (kG * 75)        // float4 count per transposed weight matrix (90000)

__device__ __forceinline__ float sigmoidf_(float v) { return 1.0f / (1.0f + expf(-v)); }

// -----------------------------------------------------------------------------
// Pre-pass: transpose [1200][300] row-major weights into k-major float4 layout
// wt[k4*1200 + r] = w[r][4k4 .. 4k4+3], so that in the GEMM inner loop lanes
// with consecutive tid (consecutive rows) read consecutive 16B chunks ->
// perfectly coalesced 1KB-per-wave global_load_dwordx4.
// -----------------------------------------------------------------------------
__global__ __launch_bounds__(256) void transpose_w(const float* __restrict__ w,
                                                   float4* __restrict__ wt) {
    int i = blockIdx.x * 256 + threadIdx.x;     // i = k4*1200 + r (write-coalesced)
    if (i >= W4) return;
    int k4 = i / kG;
    int r  = i - k4 * kG;
    const float* p = w + (size_t)r * 300 + k4 * 4;
    wt[i] = make_float4(p[0], p[1], p[2], p[3]);
}

// -----------------------------------------------------------------------------
// Fused BiLSTM: one block = (direction, 2-batch-row tile), zero inter-block
// sync. h,c live in LDS for all 256 steps. Weights stream from L2 with
// coalesced k-major loads; w_ih streaming amortized over 8-step chunks.
// Emissions written to workspace fp32 (Viterbi needs exact fp32 scores).
// -----------------------------------------------------------------------------
__global__ __launch_bounds__(256) void ner_bilstm_kernel(
    const int*    __restrict__ x,        // [B][S]
    const float*  __restrict__ emb,      // [V][E]
    const float4* __restrict__ wih4_f,   // transposed [75][1200] float4
    const float4* __restrict__ whh4_f,
    const float*  __restrict__ bih_f,
    const float*  __restrict__ bhh_f,
    const float4* __restrict__ wih4_b,
    const float4* __restrict__ whh4_b,
    const float*  __restrict__ bih_b,
    const float*  __restrict__ bhh_b,
    const float*  __restrict__ w_proj,   // [9][600]
    float*        __restrict__ em_all)   // ws: em_f then em_b, each [S][B][9]
{
    extern __shared__ float s_pre[];                 // [TCHUNK*TILE_B][kG] = 76.8 KB dynamic
    __shared__ float s_h[TILE_B][304];               // h_{t-1}
    __shared__ float s_c[TILE_B][300];
    __shared__ float s_Ax[TCHUNK * TILE_B][304];     // gathered embeddings (chunk)
    __shared__ float s_gbuf[TILE_B][kG];             // gate preacts, current step
    __shared__ float s_emp[TILE_B][kT][14];          // emission partial sums
    // total LDS ~112 KB -> 1 block/CU by construction.

    // XCD-grouped mapping: XCDs 0-3 forward, 4-7 backward => each XCD's L2 only
    // holds one direction's weights (2.88 MB < 4 MB).
    const int bi   = blockIdx.x;
    const int xcd  = bi & 7;
    const int dir  = (xcd >= 4) ? 1 : 0;
    const int tile = (bi >> 3) * 4 + (xcd & 3);      // 0..127

    const float4* wih4 = dir ? wih4_b : wih4_f;
    const float4* whh4 = dir ? whh4_b : whh4_f;
    const float*  bih  = dir ? bih_b  : bih_f;
    const float*  bhh  = dir ? bhh_b  : bhh_f;
    float* emout = em_all + (size_t)dir * EMSZ;

    const int tid = threadIdx.x;

    // per-thread bias sums for owned rows (strided ownership r = tid + j*240)
    float bsum[RPT];
    if (tid < ACT) {
#pragma unroll
        for (int j = 0; j < RPT; ++j) {
            const int r = tid + j * ACT;
            bsum[j] = bih[r] + bhh[r];
        }
    }

    for (int i = tid; i < TILE_B * 304; i += 256) (&s_h[0][0])[i] = 0.0f;
    for (int i = tid; i < TILE_B * 300; i += 256) (&s_c[0][0])[i] = 0.0f;
    __syncthreads();

    for (int tc = 0; tc < kS / TCHUNK; ++tc) {
        // ---- embedding gather for this time chunk (16 (tt,b2) rows) ------------
        {
            const int rr = tid >> 4;          // 0..15 = tt*2 + b2
            const int ln = tid & 15;
            const int tt = rr >> 1;
            const int b2 = rr & 1;
            const int t  = tc * TCHUNK + tt;
            const int s  = dir ? (kS - 1 - t) : t;
            const int bg = tile * TILE_B + b2;
            const int token = x[bg * kS + s];
            const float* erow = emb + (size_t)token * kE;
            for (int e = ln; e < kE; e += 16) s_Ax[rr][e] = erow[e];
        }
        __syncthreads();

        // ---- input projection: s_pre[q][r] = bias[r] + x_q . w_ih[r] -----------
        if (tid < ACT) {
            float acc[RPT][16];
#pragma unroll
            for (int j = 0; j < RPT; ++j)
#pragma unroll
                for (int q = 0; q < 16; ++q) acc[j][q] = bsum[j];

            const float4* wp = wih4 + tid;
            for (int kc = 0; kc < 75; ++kc) {
                float4 w[RPT];
#pragma unroll
                for (int j = 0; j < RPT; ++j) w[j] = wp[kc * kG + j * ACT];  // coalesced
#pragma unroll
                for (int q = 0; q < 16; ++q) {
                    const float4 a = *(const float4*)&s_Ax[q][kc * 4];       // broadcast
#pragma unroll
                    for (int j = 0; j < RPT; ++j)
                        acc[j][q] += w[j].x * a.x + w[j].y * a.y + w[j].z * a.z + w[j].w * a.w;
                }
            }
#pragma unroll
            for (int j = 0; j < RPT; ++j) {
                const int r = tid + j * ACT;
#pragma unroll
                for (int q = 0; q < 16; ++q) s_pre[q * kG + r] = acc[j][q];
            }
        }
        __syncthreads();

        // ---- recurrent steps within the chunk ----------------------------------
        for (int tt = 0; tt < TCHUNK; ++tt) {
            const int t = tc * TCHUNK + tt;
            const int s = dir ? (kS - 1 - t) : t;

            // gates = pre + h_{t-1} @ w_hh^T  (w stream double-buffered in regs)
            if (tid < ACT) {
                float acc0[RPT], acc1[RPT];
#pragma unroll
                for (int j = 0; j < RPT; ++j) {
                    const int r = tid + j * ACT;
                    acc0[j] = s_pre[(tt * 2 + 0) * kG + r];
                    acc1[j] = s_pre[(tt * 2 + 1) * kG + r];
                }
                const float4* wp = whh4 + tid;
                float4 wc[RPT];
#pragma unroll
                for (int j = 0; j < RPT; ++j) wc[j] = wp[j * ACT];
                for (int kc = 0; kc < 74; ++kc) {
                    float4 wn[RPT];
#pragma unroll
                    for (int j = 0; j < RPT; ++j) wn[j] = wp[(kc + 1) * kG + j * ACT];
                    const float4 a0 = *(const float4*)&s_h[0][kc * 4];
                    const float4 a1 = *(const float4*)&s_h[1][kc * 4];
#pragma unroll
                    for (int j = 0; j < RPT; ++j) {
                        acc0[j] += wc[j].x * a0.x + wc[j].y * a0.y + wc[j].z * a0.z + wc[j].w * a0.w;
                        acc1[j] += wc[j].x * a1.x + wc[j].y * a1.y + wc[j].z * a1.z + wc[j].w * a1.w;
                    }
#pragma unroll
                    for (int j = 0; j < RPT; ++j) wc[j] = wn[j];
                }
                {   // kc = 74 tail
                    const float4 a0 = *(const float4*)&s_h[0][74 * 4];
                    const float4 a1 = *(const float4*)&s_h[1][74 * 4];
#pragma unroll
                    for (int j = 0; j < RPT; ++j) {
                        acc0[j] += wc[j].x * a0.x + wc[j].y * a0.y + wc[j].z * a0.z + wc[j].w * a0.w;
                        acc1[j] += wc[j].x * a1.x + wc[j].y * a1.y + wc[j].z * a1.z + wc[j].w * a1.w;
                    }
                }
#pragma unroll
                for (int j = 0; j < RPT; ++j) {
                    const int r = tid + j * ACT;
                    s_gbuf[0][r] = acc0[j];
                    s_gbuf[1][r] = acc1[j];
                }
            }
            __syncthreads();

            // elementwise LSTM cell update (PyTorch gate order i,f,g,o)
#pragma unroll
            for (int rep = 0; rep < 2; ++rep) {
                const int nn = tid + rep * 256;
                if (nn < kH) {
#pragma unroll
                    for (int b2 = 0; b2 < TILE_B; ++b2) {
                        const float gi = s_gbuf[b2][nn];
                        const float gf = s_gbuf[b2][nn + 300];
                        const float gg = s_gbuf[b2][nn + 600];
                        const float go = s_gbuf[b2][nn + 900];
                        const float c  = sigmoidf_(gf) * s_c[b2][nn] + sigmoidf_(gi) * tanhf(gg);
                        const float h  = sigmoidf_(go) * tanhf(c);
                        s_c[b2][nn] = c;
                        s_h[b2][nn] = h;
                    }
                }
            }
            __syncthreads();

            // emission partials: em[s][b][tag] = sum_n h[b][n] * w_proj[tag][dir*300+n]
            if (tid < 252) {
                const int b2  = tid / 126;
                const int rem = tid % 126;
                const int tag = rem / 14;
                const int ch  = rem % 14;
                const int n0  = ch * 22;
                const int n1  = (n0 + 22 < 300) ? n0 + 22 : 300;
                const float* wrow = w_proj + tag * (2 * kH) + dir * kH;
                float sum = 0.0f;
                for (int n = n0; n < n1; ++n) sum += s_h[b2][n] * wrow[n];
                s_emp[b2][tag][ch] = sum;
            }
            __syncthreads();

            if (tid < TILE_B * kT) {
                const int b2  = tid / kT;
                const int tag = tid % kT;
                float sum = 0.0f;
#pragma unroll
                for (int ch = 0; ch < 14; ++ch) sum += s_emp[b2][tag][ch];
                const int bg = tile * TILE_B + b2;
                emout[((size_t)s * kB + bg) * kT + tag] = sum;
            }
            // no barrier needed: next phase writes s_gbuf/s_Ax, disjoint from s_emp
        }
    }
}

// -----------------------------------------------------------------------------
// CRF Viterbi decode. 9 lanes per batch row (7 groups/wave, 28 rows/block).
// Cross-lane max via __shfl; backpointers in LDS; first-max ties = np.argmax.
// -----------------------------------------------------------------------------
__global__ __launch_bounds__(256) void ner_viterbi_kernel(
    const float* __restrict__ em_all,
    const float* __restrict__ b_proj,
    const float* __restrict__ start_t,
    const float* __restrict__ end_t,
    const float* __restrict__ trans,
    int*         __restrict__ out)
{
    const float* em_f = em_all;
    const float* em_b = em_all + EMSZ;

    __shared__ uint8_t bp[kS - 1][28][kT];

    const int tid  = threadIdx.x;
    const int wave = tid >> 6;
    const int lane = tid & 63;
    const int g    = lane / kT;
    const int nx   = lane % kT;
    const bool active = (g < 7);
    const int gg   = wave * 7 + g;
    const int b    = blockIdx.x * 28 + (active ? gg : 0);
    const bool valid = active && (b < kB);
    const int beff = (b < kB) ? b : (kB - 1);
    const int base = g * kT;

    float tcol[kT];
#pragma unroll
    for (int p = 0; p < kT; ++p) tcol[p] = trans[p * kT + nx];
    const float bpj = b_proj[nx];

    float score = start_t[nx]
                + em_f[(size_t)beff * kT + nx]
                + em_b[(size_t)beff * kT + nx]
                + bpj;

    for (int t = 1; t < kS; ++t) {
        const size_t ei = ((size_t)t * kB + beff) * kT + nx;
        const float em = em_f[ei] + em_b[ei] + bpj;
        float best = -3.402823466e38f;
        int bidx = 0;
#pragma unroll
        for (int p = 0; p < kT; ++p) {
            const float sp = __shfl(score, base + p, 64);
            const float cand = sp + tcol[p];
            if (cand > best) { best = cand; bidx = p; }
        }
        if (valid) bp[t - 1][gg][nx] = (uint8_t)bidx;
        score = best + em;
    }

    score += end_t[nx];
    float best = -3.402823466e38f;
    int last = 0;
#pragma unroll
    for (int p = 0; p < kT; ++p) {
        const float sp = __shfl(score, base + p, 64);
        if (sp > best) { best = sp; last = p; }
    }

    __syncthreads();

    if (valid && nx == 0) {
        int cur = last;
        out[beff * kS + (kS - 1)] = cur;
        for (int t = kS - 2; t >= 0; --t) {
            cur = bp[t][gg][cur];
            out[beff * kS + t] = cur;
        }
    }
}

// -----------------------------------------------------------------------------
extern "C" void kernel_launch(void* const* d_in, const int* in_sizes, int n_in,
                              void* d_out, int out_size, void* d_ws, size_t ws_size,
                              hipStream_t stream) {
    const int*   x       = (const int*)  d_in[0];
    const float* emb     = (const float*)d_in[1];
    const float* w_ih_f  = (const float*)d_in[2];
    const float* w_hh_f  = (const float*)d_in[3];
    const float* b_ih_f  = (const float*)d_in[4];
    const float* b_hh_f  = (const float*)d_in[5];
    const float* w_ih_b  = (const float*)d_in[6];
    const float* w_hh_b  = (const float*)d_in[7];
    const float* b_ih_b  = (const float*)d_in[8];
    const float* b_hh_b  = (const float*)d_in[9];
    const float* w_proj  = (const float*)d_in[10];
    const float* b_proj  = (const float*)d_in[11];
    const float* start_t = (const float*)d_in[12];
    const float* end_t   = (const float*)d_in[13];
    const float* trans   = (const float*)d_in[14];

    // workspace layout: em (4.72 MB) | 4 transposed weight matrices (5.76 MB)
    float*  em_all  = (float*)d_ws;
    float4* wt_base = (float4*)((char*)d_ws + (size_t)2 * EMSZ * 4);
    float4* wt_ihf  = wt_base;
    float4* wt_hhf  = wt_base + W4;
    float4* wt_ihb  = wt_base + 2 * W4;
    float4* wt_hhb  = wt_base + 3 * W4;

    const int tgrid = (W4 + 255) / 256;
    transpose_w<<<tgrid, 256, 0, stream>>>(w_ih_f, wt_ihf);
    transpose_w<<<tgrid, 256, 0, stream>>>(w_hh_f, wt_hhf);
    transpose_w<<<tgrid, 256, 0, stream>>>(w_ih_b, wt_ihb);
    transpose_w<<<tgrid, 256, 0, stream>>>(w_hh_b, wt_hhb);

    // 256 blocks (2 dirs x 128 tiles); 76.8 KB dynamic LDS (s_pre) + ~35 KB static
    ner_bilstm_kernel<<<256, 256, TCHUNK * TILE_B * kG * sizeof(float), stream>>>(
        x, emb, wt_ihf, wt_hhf, b_ih_f, b_hh_f,
        wt_ihb, wt_hhb, b_ih_b, b_hh_b, w_proj, em_all);

    ner_viterbi_kernel<<<10, 256, 0, stream>>>(
        em_all, (const float*)d_in[11], start_t, end_t, trans, (int*)d_out);
}